// Round 18
// baseline (87.584 us; speedup 1.0000x reference)
//
#include <hip/hip_runtime.h>

// ---------------- constants ----------------
constexpr int kH = 192, kW = 256, kHW = kH * kW;
constexpr int kFH = 48, kFW = 64, kFHW = kFH * kFW;
constexpr int kMH = 39, kMW = 51;
constexpr int kL = kMH * kMW;          // 1989
constexpr int kLP = 2048;              // padded q length
constexpr int kHeads = 32;
constexpr int kPT = 128;               // padded p/q tiles of 16
constexpr float kInitH = 256.0f / 5.0f;
constexpr float kInitW = 192.0f / 5.0f;
constexpr float kL2E = 1.44269504088896340736f;
constexpr float kBias = -16.0f;        // log2-domain bias (cancels in n/den)
constexpr float kPadCorr = 59.0f / 65536.0f;   // 59 * 2^-16, exact (power-of-2 e, trunc-exact)

typedef unsigned long long u64;
typedef short s4 __attribute__((ext_vector_type(4)));
typedef float f4 __attribute__((ext_vector_type(4)));

__device__ __forceinline__ s4 u2s(u64 x) { union { u64 u; s4 s; } c; c.u = x; return c.s; }

// D = A(16x16 bf16) * B(16x16 bf16) + C ; A: m=lane&15,k=(lane>>4)*4+j ;
// B: n=lane&15,k=(lane>>4)*4+j ; C/D: col=lane&15, row=(lane>>4)*4+reg (verified R16)
__device__ __forceinline__ f4 mfma16(s4 a, s4 b, f4 c) {
#if __has_builtin(__builtin_amdgcn_mfma_f32_16x16x16bf16_1k)
  return __builtin_amdgcn_mfma_f32_16x16x16bf16_1k(a, b, c, 0, 0, 0);
#else
  f4 d;
  asm("v_mfma_f32_16x16x16_bf16 %0, %1, %2, %3" : "=v"(d) : "v"(a), "v"(b), "v"(c));
  return d;
#endif
}

__device__ __forceinline__ float fast_exp2(float x) {
#if __has_builtin(__builtin_amdgcn_exp2f)
  return __builtin_amdgcn_exp2f(x);
#else
  float r; asm("v_exp_f32 %0, %1\n\ts_nop 1" : "=v"(r) : "v"(x)); return r;
#endif
}

// truncation pack: 4 f32 -> 4 bf16 (B-fragment word). 6 VALU ops, no asm
// (R17's inline-asm v_cvt_pk_bf16_f32 produced garbage -> NaN; guide m240: don't hand-write cvt_pk).
// Truncation error <= 0.4% on E, cancels in n/den; pad e = 2^-16 stays exact.
__device__ __forceinline__ s4 packE(float e0, float e1, float e2, float e3) {
  unsigned u0 = __float_as_uint(e0), u1 = __float_as_uint(e1);
  unsigned u2 = __float_as_uint(e2), u3 = __float_as_uint(e3);
  union { unsigned u[2]; s4 s; } c;
  c.u[0] = (u0 >> 16) | (u1 & 0xFFFF0000u);
  c.u[1] = (u2 >> 16) | (u3 & 0xFFFF0000u);
  return c.s;
}

// fp32 -> bf16 (RTNE) and back (used in k_patch only)
__device__ __forceinline__ unsigned f2bfu(float f) {
  unsigned u = __float_as_uint(f);
  return (u + 0x7FFFu + ((u >> 16) & 1u)) >> 16;
}
__device__ __forceinline__ float bfuf(unsigned h) { return __uint_as_float(h << 16); }
__device__ __forceinline__ u64 pack4(unsigned h0, unsigned h1, unsigned h2, unsigned h3) {
  return (u64)(h0 | (h1 << 16)) | ((u64)(h2 | (h3 << 16)) << 32);
}

struct HeadParams {
  int use;
  int ntop_c, nleft_c, nh_c, nw_c, dy1_c, dx1_c;
  int ntop_p, nleft_p, nh_p, nw_p, dy1_p, dx1_p;
  float h_c, w_c, h_p, w_p;
};

__device__ __forceinline__ float sigf(float x) { return 1.0f / (1.0f + __expf(-x)); }
__device__ __forceinline__ float stepH(int j) { return (float)(2 * abs(j - 19) + 1); }
__device__ __forceinline__ float stepW(int j) { return (float)(2 * abs(j - 25) + 1); }

__device__ void headParams(int i, const int* clm, const int* plm, const float* sp, HeadParams& h) {
  int ccx = clm[2 * i], ccy = clm[2 * i + 1];
  int pcx = plm[2 * i], pcy = plm[2 * i + 1];
  h.use = !(((ccx == 0) && (ccy == 0)) || ((pcx == 0) && (pcy == 0)));
  {
    int top = ccy - 20, bottom = ccy + 19;
    int left = ccx - 26, right = ccx + 25;
    int dy1 = max(-top, 0), dy2 = max(bottom - kH, 0);
    int dx1 = max(-left, 0), dx2 = max(right - kW, 0);
    h.ntop_c = top + dy1; h.nleft_c = left + dx1; h.dy1_c = dy1; h.dx1_c = dx1;
    h.nh_c = max(kMH - dy1 - dy2, 0); h.nw_c = max(kMW - dx1 - dx2, 0);
  }
  {
    int top = pcy - 20, bottom = pcy + 19;
    int left = pcx - 26, right = pcx + 25;
    int dy1 = max(-top, 0), dy2 = max(bottom - kH, 0);
    int dx1 = max(-left, 0), dx2 = max(right - kW, 0);
    h.ntop_p = top + dy1; h.nleft_p = left + dx1; h.dy1_p = dy1; h.dx1_p = dx1;
    h.nh_p = max(kMH - dy1 - dy2, 0); h.nw_p = max(kMW - dx1 - dx2, 0);
  }
  float adj_cw = sp[4 * i + 0], adj_ch = sp[4 * i + 1];
  float adj_pw = sp[4 * i + 2], adj_ph = sp[4 * i + 3];
  h.h_c = kInitH * sigf(adj_ch);
  h.w_c = kInitW * sigf(adj_cw);
  h.h_p = kInitH * sigf(adj_ph);
  h.w_p = kInitW * sigf(adj_pw);
}

// on-the-fly 64->4 prelu + 1x1 conv, scaled by s
__device__ __forceinline__ float4 conv4(const float* __restrict__ f, const float* __restrict__ w,
                                        const float* __restrict__ b, float a, int fpix, float s) {
  float acc0 = 0.f, acc1 = 0.f, acc2 = 0.f, acc3 = 0.f;
#pragma unroll 8
  for (int c = 0; c < 64; ++c) {
    float x = f[c * kFHW + fpix];
    float pr = fmaxf(x, 0.f) + a * fminf(x, 0.f);
    acc0 = fmaf(pr, w[c], acc0);
    acc1 = fmaf(pr, w[64 + c], acc1);
    acc2 = fmaf(pr, w[128 + c], acc2);
    acc3 = fmaf(pr, w[192 + c], acc3);
  }
  return make_float4((acc0 + b[0]) * s, (acc1 + b[1]) * s, (acc2 + b[2]) * s, (acc3 + b[3]) * s);
}

// split a float4 into bf16 hi/lo fragment words
__device__ __forceinline__ void split4(float4 v, u64& hi, u64& lo) {
  unsigned h0 = f2bfu(v.x), h1 = f2bfu(v.y), h2 = f2bfu(v.z), h3 = f2bfu(v.w);
  unsigned l0 = f2bfu(v.x - bfuf(h0)), l1 = f2bfu(v.y - bfuf(h1));
  unsigned l2 = f2bfu(v.z - bfuf(h2)), l3 = f2bfu(v.w - bfuf(h3));
  hi = pack4(h0, h1, h2, h3);
  lo = pack4(l0, l1, l2, l3);
}

// -------- k_patch: role A (bx<8): K/P fragments + head params; role B: V fragments --------
__global__ void k_patch(const float* __restrict__ fc, const float* __restrict__ fp,
                        const float* __restrict__ w1, const float* __restrict__ b1, const float* __restrict__ a1,
                        const float* __restrict__ w2, const float* __restrict__ b2, const float* __restrict__ a2,
                        const float* __restrict__ loc,
                        const float* __restrict__ sp, const int* __restrict__ clm, const int* __restrict__ plm,
                        u64* __restrict__ Ph, u64* __restrict__ Pl,
                        u64* __restrict__ Kh, u64* __restrict__ Kl,
                        u64* __restrict__ Vh, u64* __restrict__ Vl,
                        int* __restrict__ hpws) {
  int i = blockIdx.y;
  int bx = blockIdx.x;
  if (bx < 8) {
    // ---- role A: per-q K fragments, per-p P fragments ----
    __shared__ int shp[20];
    if (threadIdx.x == 0) {
      HeadParams h; headParams(i, clm, plm, sp, h);
      shp[0] = h.use;
      shp[1] = h.ntop_c; shp[2] = h.nleft_c; shp[3] = h.nh_c; shp[4] = h.nw_c; shp[5] = h.dy1_c; shp[6] = h.dx1_c;
      shp[7] = h.ntop_p; shp[8] = h.nleft_p; shp[9] = h.nh_p; shp[10] = h.nw_p; shp[11] = h.dy1_p; shp[12] = h.dx1_p;
      shp[13] = __float_as_int(h.h_c); shp[14] = __float_as_int(h.w_c);
      shp[15] = __float_as_int(h.h_p); shp[16] = __float_as_int(h.w_p);
      if (bx == 0) {
        int* o = hpws + i * 20;
#pragma unroll
        for (int t = 0; t < 17; ++t) o[t] = shp[t];
      }
    }
    __syncthreads();
    int use = shp[0];
    int ntop_c = shp[1], nleft_c = shp[2], nh_c = shp[3], nw_c = shp[4], dy1_c = shp[5], dx1_c = shp[6];
    int ntop_p = shp[7], nleft_p = shp[8], nh_p = shp[9], nw_p = shp[10], dy1_p = shp[11], dx1_p = shp[12];
    float h_c = __int_as_float(shp[13]), w_c = __int_as_float(shp[14]);
    float h_p = __int_as_float(shp[15]), w_p = __int_as_float(shp[16]);

    int q = bx * 256 + threadIdx.x;        // [0, 2048)
    int qr = q / kMW, qc = q - qr * kMW;
    int fi = (i * kPT + (q >> 4)) * 16 + (q & 15);
    // K fragment (c-side), q >= kL or invalid -> zeros
    {
      bool val = (q < kL) && use && (qr < nh_c) && (qc < nw_c);
      float4 kv = make_float4(0.f, 0.f, 0.f, 0.f);
      if (val) {
        int row = min(ntop_c + qr, kH - 1);
        int col = min(nleft_c + qc, kW - 1);
        int mr = min(dy1_c + qr, kMH - 1);
        int mc = min(dx1_c + qc, kMW - 1);
        float mv = sigf((h_c - stepH(mr)) * 2.f) * sigf((w_c - stepW(mc)) * 2.f);
        int fpix = (row >> 2) * kFW + (col >> 2);
        kv = conv4(fc, w1, b1, a1[0], fpix, mv);
      }
      u64 hi, lo; split4(kv, hi, lo);
      Kh[fi] = hi; Kl[fi] = lo;
    }
    // P fragment (p-side, pre-scaled by log2e), p >= kL or invalid -> zeros
    {
      bool val = (q < kL) && use && (qr < nh_p) && (qc < nw_p);
      float4 pv = make_float4(0.f, 0.f, 0.f, 0.f);
      if (val) {
        int row = min(ntop_p + qr, kH - 1);
        int col = min(nleft_p + qc, kW - 1);
        int mr = min(dy1_p + qr, kMH - 1);
        int mc = min(dx1_p + qc, kMW - 1);
        float mv = sigf((h_p - stepH(mr)) * 2.f) * sigf((w_p - stepW(mc)) * 2.f) * kL2E;
        int fpix = (row >> 2) * kFW + (col >> 2);
        pv = conv4(fp, w2, b2, a2[0], fpix, mv);
      }
      u64 hi, lo; split4(pv, hi, lo);
      Ph[fi] = hi; Pl[fi] = lo;
    }
  } else {
    // ---- role B: V fragments (A-operand of PV mfma): lane l holds V[m=l&15][q=qt*16+(l>>4)*4+j]
    int idx = (bx - 8) * 256 + threadIdx.x;  // [0, 8192)
    int l = idx & 63, qt = idx >> 6;
    int m = l & 15, g = l >> 4;
    u64 hi = 0, lo = 0;
    if (m == 0) {
      hi = 0x3F803F803F803F80ULL;           // four bf16 1.0 (den row)
    } else if (m <= 2) {
      int ccx = clm[2 * i], ccy = clm[2 * i + 1];
      int pcx = plm[2 * i], pcy = plm[2 * i + 1];
      int use = !(((ccx == 0) && (ccy == 0)) || ((pcx == 0) && (pcy == 0)));
      int top = ccy - 20, left = ccx - 26;
      int dy1 = max(-top, 0), dx1 = max(-left, 0);
      int dy2 = max(ccy + 19 - kH, 0), dx2 = max(ccx + 25 - kW, 0);
      int ntop = top + dy1, nleft = left + dx1;
      int nh = max(kMH - dy1 - dy2, 0), nw = max(kMW - dx1 - dx2, 0);
      const float* lp = loc + (2 * i + (m - 1)) * kHW;
#pragma unroll
      for (int j = 0; j < 4; ++j) {
        int q = qt * 16 + g * 4 + j;
        int qr = q / kMW, qc = q - qr * kMW;
        bool val = (q < kL) && use && (qr < nh) && (qc < nw);
        int row = min(ntop + qr, kH - 1);
        int col = min(nleft + qc, kW - 1);
        float v = val ? lp[row * kW + col] : -1.0f;
        unsigned hb = f2bfu(v);
        unsigned lb = f2bfu(v - bfuf(hb));
        hi |= (u64)hb << (16 * j);
        lo |= (u64)lb << (16 * j);
      }
    }
    int o = (i * kPT + qt) * 64 + l;
    Vh[o] = hi; Vl[o] = lo;
  }
}

// -------- MFMA flash attention: per wave = (head, p-tile, q-half of 64 tiles) --------
__global__ void __launch_bounds__(256) k_attn_mfma(const u64* __restrict__ Ph, const u64* __restrict__ Pl,
                                                   const u64* __restrict__ Kh, const u64* __restrict__ Kl,
                                                   const u64* __restrict__ Vh, const u64* __restrict__ Vl,
                                                   float4* __restrict__ pPart) {
  int bid = blockIdx.x;                    // 2048 blocks
  int i = bid >> 6;                        // head
  int r = bid & 63;
  int h = r & 1;                           // q-half
  int ptb = (r >> 1) << 2;                 // base p-tile (4 consecutive per block)
  int wid = threadIdx.x >> 6;
  int lane = threadIdx.x & 63;
  int pt = ptb + wid;
  bool l16 = lane < 16;

  u64 phw = l16 ? Ph[(i * kPT + pt) * 16 + lane] : 0ULL;
  u64 plw = l16 ? Pl[(i * kPT + pt) * 16 + lane] : 0ULL;
  s4 bPh = u2s(phw), bPl = u2s(plw);

  int t0 = h * 64;
  const u64* kh = Kh + (size_t)(i * kPT + t0) * 16;
  const u64* kl = Kl + (size_t)(i * kPT + t0) * 16;
  const u64* vh = Vh + (size_t)(i * kPT + t0) * 64;
  const u64* vl = Vl + (size_t)(i * kPT + t0) * 64;

  f4 acc0 = {0.f, 0.f, 0.f, 0.f};          // even t chain
  f4 acc1 = {0.f, 0.f, 0.f, 0.f};          // odd t chain (breaks serial PV dependency)
#pragma unroll 4
  for (int t = 0; t < 64; t += 2) {
    // ---- even ----
    u64 akh0 = l16 ? kh[t * 16 + lane] : 0ULL;
    u64 akl0 = l16 ? kl[t * 16 + lane] : 0ULL;
    u64 avh0 = vh[t * 64 + lane];
    u64 avl0 = vl[t * 64 + lane];
    // ---- odd ----
    u64 akh1 = l16 ? kh[(t + 1) * 16 + lane] : 0ULL;
    u64 akl1 = l16 ? kl[(t + 1) * 16 + lane] : 0ULL;
    u64 avh1 = vh[(t + 1) * 64 + lane];
    u64 avl1 = vl[(t + 1) * 64 + lane];

    f4 s0 = {kBias, kBias, kBias, kBias};
    s0 = mfma16(u2s(akh0), bPl, s0);
    s0 = mfma16(u2s(akl0), bPh, s0);
    s0 = mfma16(u2s(akh0), bPh, s0);
    f4 s1 = {kBias, kBias, kBias, kBias};
    s1 = mfma16(u2s(akh1), bPl, s1);
    s1 = mfma16(u2s(akl1), bPh, s1);
    s1 = mfma16(u2s(akh1), bPh, s1);

    s4 E0 = packE(fast_exp2(s0.x), fast_exp2(s0.y), fast_exp2(s0.z), fast_exp2(s0.w));
    s4 E1 = packE(fast_exp2(s1.x), fast_exp2(s1.y), fast_exp2(s1.z), fast_exp2(s1.w));

    acc0 = mfma16(u2s(avl0), E0, acc0);
    acc0 = mfma16(u2s(avh0), E0, acc0);
    acc1 = mfma16(u2s(avl1), E1, acc1);
    acc1 = mfma16(u2s(avh1), E1, acc1);
  }
  f4 acc = acc0 + acc1;
  // D rows 0..2 (lanes 0-15, regs 0-2): den, nx, ny for p = pt*16 + lane
  if (l16) {
    pPart[((size_t)(i * kPT + pt) * 2 + h) * 16 + lane] = make_float4(acc.x, acc.y, acc.z, 0.f);
  }
}

// -------- full-image merge: init + 2-partial merge + inverse-map scatter --------
__global__ void k_merge_full(const float4* __restrict__ pPart,
                             const int* __restrict__ hpws, float* __restrict__ out) {
  int i = blockIdx.y;
  int pix = blockIdx.x * 256 + threadIdx.x;
  const int* hp = hpws + i * 20;
  int use = hp[0];
  int ntop_p = hp[7], nleft_p = hp[8], nh_p = hp[9], nw_p = hp[10];
  int r = pix >> 8;
  int c = pix & 255;
  int pr = r - ntop_p, pc = c - nleft_p;
  bool val = use && ((unsigned)pr < (unsigned)nh_p) && ((unsigned)pc < (unsigned)nw_p);
  float f0 = -1.f, f1 = -1.f, mk = 0.f;
  if (val) {
    int p = pr * kMW + pc;
    int pt = p >> 4, lq = p & 15;
    size_t base = ((size_t)(i * kPT + pt) * 2) * 16 + lq;
    float4 t0 = pPart[base];
    float4 t1 = pPart[base + 16];
    float den = t0.x + t1.x - kPadCorr;
    float n0 = t0.y + t1.y + kPadCorr;
    float n1 = t0.z + t1.z + kPadCorr;
    float inv = 1.0f / den;
    f0 = n0 * inv; f1 = n1 * inv; mk = 1.0f;
  }
  out[(2 * i) * kHW + pix]      = f0;
  out[(2 * i + 1) * kHW + pix]  = f1;
  out[64 * kHW + i * kHW + pix] = mk;
}

extern "C" void kernel_launch(void* const* d_in, const int* in_sizes, int n_in,
                              void* d_out, int out_size, void* d_ws, size_t ws_size,
                              hipStream_t stream) {
  (void)in_sizes; (void)n_in; (void)out_size; (void)ws_size;
  const float* loc = (const float*)d_in[0];
  const float* fc  = (const float*)d_in[1];
  const float* fp  = (const float*)d_in[2];
  const float* sp  = (const float*)d_in[3];
  const int* clm   = (const int*)d_in[6];
  const int* plm   = (const int*)d_in[7];
  const float* w1  = (const float*)d_in[8];
  const float* b1  = (const float*)d_in[9];
  const float* a1  = (const float*)d_in[10];
  const float* w2  = (const float*)d_in[11];
  const float* b2  = (const float*)d_in[12];
  const float* a2  = (const float*)d_in[13];
  float* out = (float*)d_out;
  char* ws = (char*)d_ws;

  // workspace layout (8B aligned)
  int* hpws = (int*)(ws);                          //      4,096 B
  u64* Ph   = (u64*)(ws + 4096);                   //    524,288 B  [32][128][16]
  u64* Pl   = (u64*)(ws + 528384);                 //    524,288 B
  u64* Kh   = (u64*)(ws + 1052672);                //    524,288 B
  u64* Kl   = (u64*)(ws + 1576960);                //    524,288 B
  u64* Vh   = (u64*)(ws + 2101248);                //  2,097,152 B  [32][128][64]
  u64* Vl   = (u64*)(ws + 4198400);                //  2,097,152 B
  float4* pPart = (float4*)(ws + 6295552);         //  2,097,152 B  [32][128][2][16]

  k_patch<<<dim3(40, kHeads), 256, 0, stream>>>(fc, fp, w1, b1, a1, w2, b2, a2,
                                                loc, sp, clm, plm,
                                                Ph, Pl, Kh, Kl, Vh, Vl, hpws);
  k_attn_mfma<<<2048, 256, 0, stream>>>(Ph, Pl, Kh, Kl, Vh, Vl, pPart);
  k_merge_full<<<dim3(kHW / 256, kHeads), 256, 0, stream>>>(pPart, hpws, out);
}

// Round 19
// 55.882 us; speedup vs baseline: 1.5673x; 1.5673x over previous
//
#include <hip/hip_runtime.h>

// ---------------- constants ----------------
constexpr int kH = 192, kW = 256, kHW = kH * kW;
constexpr int kFH = 48, kFW = 64, kFHW = kFH * kFW;
constexpr int kMH = 39, kMW = 51;
constexpr int kL = kMH * kMW;          // 1989
constexpr int kLP = 2048;              // padded q length
constexpr int kHeads = 32;
constexpr float kInitH = 256.0f / 5.0f; // init_h = W/INIT_SCALE
constexpr float kInitW = 192.0f / 5.0f; // init_w = H/INIT_SCALE
constexpr float kL2E = 1.44269504088896340736f;
constexpr float kBias = -16.0f;        // log2-domain bias (cancels in n/den)
// pad q (kL..kLP): K=0 -> e = 2^kBias exactly; V=(-1,-1). Analytic removal:
constexpr float kPadCorr = 59.0f / 65536.0f;   // 59 * 2^-16, exact in fp32

typedef float v2f __attribute__((ext_vector_type(2)));
__device__ __forceinline__ v2f pkfma(v2f a, v2f b, v2f c) {
  return __builtin_elementwise_fma(a, b, c);
}

// raw hardware exp2: args in [-40, 0] — no denormal/range fixup needed.
__device__ __forceinline__ float fast_exp2(float x) {
#if __has_builtin(__builtin_amdgcn_exp2f)
  return __builtin_amdgcn_exp2f(x);
#else
  float r;
  asm("v_exp_f32 %0, %1\n\ts_nop 1" : "=v"(r) : "v"(x));
  return r;
#endif
}

struct HeadParams {
  int use;
  int ntop_c, nleft_c, nh_c, nw_c, dy1_c, dx1_c;   // ntop = new_top = max(top,0)
  int ntop_p, nleft_p, nh_p, nw_p, dy1_p, dx1_p;
  float h_c, w_c, h_p, w_p;
};

__device__ __forceinline__ float sigf(float x) { return 1.0f / (1.0f + __expf(-x)); }
__device__ __forceinline__ float stepH(int j) { return (float)(2 * abs(j - 19) + 1); }
__device__ __forceinline__ float stepW(int j) { return (float)(2 * abs(j - 25) + 1); }

__device__ void headParams(int i, const int* clm, const int* plm, const float* sp, HeadParams& h) {
  int ccx = clm[2 * i], ccy = clm[2 * i + 1];
  int pcx = plm[2 * i], pcy = plm[2 * i + 1];
  h.use = !(((ccx == 0) && (ccy == 0)) || ((pcx == 0) && (pcy == 0)));
  {
    int top = ccy - (kMH + 1) / 2, bottom = ccy + kMH / 2;
    int left = ccx - (kMW + 1) / 2, right = ccx + kMW / 2;
    int dy1 = max(-top, 0), dy2 = max(bottom - kH, 0);
    int dx1 = max(-left, 0), dx2 = max(right - kW, 0);
    h.ntop_c = top + dy1; h.nleft_c = left + dx1; h.dy1_c = dy1; h.dx1_c = dx1;
    h.nh_c = max(kMH - dy1 - dy2, 0); h.nw_c = max(kMW - dx1 - dx2, 0);
  }
  {
    int top = pcy - (kMH + 1) / 2, bottom = pcy + kMH / 2;
    int left = pcx - (kMW + 1) / 2, right = pcx + kMW / 2;
    int dy1 = max(-top, 0), dy2 = max(bottom - kH, 0);
    int dx1 = max(-left, 0), dx2 = max(right - kW, 0);
    h.ntop_p = top + dy1; h.nleft_p = left + dx1; h.dy1_p = dy1; h.dx1_p = dx1;
    h.nh_p = max(kMH - dy1 - dy2, 0); h.nw_p = max(kMW - dx1 - dx2, 0);
  }
  float adj_cw = sp[4 * i + 0], adj_ch = sp[4 * i + 1];
  float adj_pw = sp[4 * i + 2], adj_ph = sp[4 * i + 3];
  h.h_c = kInitH * sigf(adj_ch);
  h.w_c = kInitW * sigf(adj_cw);
  h.h_p = kInitH * sigf(adj_ph);
  h.w_p = kInitW * sigf(adj_pw);
}

// on-the-fly 64->4 prelu + 1x1 conv at one quarter-res pixel, scaled by s
__device__ __forceinline__ float4 conv4(const float* __restrict__ f, const float* __restrict__ w,
                                        const float* __restrict__ b, float a, int fpix, float s) {
  float acc0 = 0.f, acc1 = 0.f, acc2 = 0.f, acc3 = 0.f;
#pragma unroll 8
  for (int c = 0; c < 64; ++c) {
    float x = f[c * kFHW + fpix];
    float pr = fmaxf(x, 0.f) + a * fminf(x, 0.f);
    acc0 = fmaf(pr, w[c], acc0);
    acc1 = fmaf(pr, w[64 + c], acc1);
    acc2 = fmaf(pr, w[128 + c], acc2);
    acc3 = fmaf(pr, w[192 + c], acc3);
  }
  return make_float4((acc0 + b[0]) * s, (acc1 + b[1]) * s, (acc2 + b[2]) * s, (acc3 + b[3]) * s);
}

// -------- fused: head params (block-level) + on-the-fly conv + patch materialization --------
// K planes: Kpl[c][i][q] c=0..3, plane stride 32*2048. V planes: Vpl[d][i][q] d=0..1.
__global__ void k_patch(const float* __restrict__ fc, const float* __restrict__ fp,
                        const float* __restrict__ w1, const float* __restrict__ b1, const float* __restrict__ a1,
                        const float* __restrict__ w2, const float* __restrict__ b2, const float* __restrict__ a2,
                        const float* __restrict__ loc,
                        const float* __restrict__ sp, const int* __restrict__ clm, const int* __restrict__ plm,
                        float* __restrict__ Kpl, float* __restrict__ Vpl, float4* __restrict__ Pall,
                        int* __restrict__ hpws) {
  __shared__ int shp[20];
  int i = blockIdx.y;
  if (threadIdx.x == 0) {
    HeadParams h; headParams(i, clm, plm, sp, h);
    shp[0] = h.use;
    shp[1] = h.ntop_c; shp[2] = h.nleft_c; shp[3] = h.nh_c; shp[4] = h.nw_c; shp[5] = h.dy1_c; shp[6] = h.dx1_c;
    shp[7] = h.ntop_p; shp[8] = h.nleft_p; shp[9] = h.nh_p; shp[10] = h.nw_p; shp[11] = h.dy1_p; shp[12] = h.dx1_p;
    shp[13] = __float_as_int(h.h_c); shp[14] = __float_as_int(h.w_c);
    shp[15] = __float_as_int(h.h_p); shp[16] = __float_as_int(h.w_p);
    if (blockIdx.x == 0) {       // persist for k_merge_full (read after this kernel completes)
      int* o = hpws + i * 20;
#pragma unroll
      for (int t = 0; t < 17; ++t) o[t] = shp[t];
    }
  }
  __syncthreads();
  int use = shp[0];
  int ntop_c = shp[1], nleft_c = shp[2], nh_c = shp[3], nw_c = shp[4], dy1_c = shp[5], dx1_c = shp[6];
  int ntop_p = shp[7], nleft_p = shp[8], nh_p = shp[9], nw_p = shp[10], dy1_p = shp[11], dx1_p = shp[12];
  float h_c = __int_as_float(shp[13]), w_c = __int_as_float(shp[14]);
  float h_p = __int_as_float(shp[15]), w_p = __int_as_float(shp[16]);

  int q = blockIdx.x * 256 + threadIdx.x;   // q in [0, 2048)
  int qr = q / kMW, qc = q - qr * kMW;
  constexpr int PS = kHeads * kLP;          // plane stride
  int o = i * kLP + q;
  float a1v = a1[0], a2v = a2[0];
  // c-side -> K, V (pad q >= kL: K=0, V=-1, corrected analytically in merge)
  {
    bool val = (q < kL) && use && (qr < nh_c) && (qc < nw_c);
    int row = min(ntop_c + qr, kH - 1);
    int col = min(nleft_c + qc, kW - 1);
    int mr = min(dy1_c + qr, kMH - 1);
    int mc = min(dx1_c + qc, kMW - 1);
    float mv = sigf((h_c - stepH(mr)) * 2.f) * sigf((w_c - stepW(mc)) * 2.f);
    int fpix = (row >> 2) * kFW + (col >> 2);
    float kx = 0.f, ky = 0.f, kz = 0.f, kw = 0.f, vx = -1.f, vy = -1.f;
    if (val) {
      float4 k = conv4(fc, w1, b1, a1v, fpix, mv);
      kx = k.x; ky = k.y; kz = k.z; kw = k.w;
      vx = loc[(2 * i) * kHW + row * kW + col];
      vy = loc[(2 * i + 1) * kHW + row * kW + col];
    }
    Kpl[o] = kx; Kpl[PS + o] = ky; Kpl[2 * PS + o] = kz; Kpl[3 * PS + o] = kw;
    Vpl[o] = vx; Vpl[PS + o] = vy;
  }
  // p-side -> P (scaled by log2e so exp2 needs no extra multiply)
  if (q < kL) {
    bool val = use && (qr < nh_p) && (qc < nw_p);
    int row = min(ntop_p + qr, kH - 1);
    int col = min(nleft_p + qc, kW - 1);
    int mr = min(dy1_p + qr, kMH - 1);
    int mc = min(dx1_p + qc, kMW - 1);
    float mv = sigf((h_p - stepH(mr)) * 2.f) * sigf((w_p - stepW(mc)) * 2.f) * kL2E;
    int fpix = (row >> 2) * kFW + (col >> 2);
    float4 pv = make_float4(0.f, 0.f, 0.f, 0.f);
    if (val) pv = conv4(fp, w2, b2, a2v, fpix, mv);
    Pall[i * kL + q] = pv;
  }
}

// -------- single-pass partial softmax-attention, packed fp32, static trip count --------
// (R10/R12 proven config: QLEN=128, v2f planar loads, unroll 8, 4 chains; float4 partial store)
template<int QLEN>
__global__ void __launch_bounds__(256) k_attn_t(const float* __restrict__ Kpl, const float* __restrict__ Vpl,
                                                const float4* __restrict__ Pall,
                                                float4* __restrict__ pPart) {
  constexpr int PS = kHeads * kLP;
  int i = blockIdx.z;
  int qsi = blockIdx.y;
  int p = blockIdx.x * 249 + threadIdx.x;
  int pe = min(p, kL - 1);
  const int base = i * kLP + qsi * QLEN;
  const float* kx = Kpl + base;
  const float* ky = Kpl + PS + base;
  const float* kz = Kpl + 2 * PS + base;
  const float* kw = Kpl + 3 * PS + base;
  const float* vx = Vpl + base;
  const float* vy = Vpl + PS + base;
  float4 P = Pall[i * kL + pe];
  v2f PX = {P.x, P.x}, PY = {P.y, P.y}, PZ = {P.z, P.z}, PW = {P.w, P.w};
  const v2f B = {kBias, kBias};
  v2f dA = {0.f, 0.f}, dB = {0.f, 0.f};
  v2f xA = {0.f, 0.f}, xB = {0.f, 0.f};
  v2f yA = {0.f, 0.f}, yB = {0.f, 0.f};
#pragma unroll 8
  for (int t = 0; t < QLEN; t += 4) {
    // pair A: q = t, t+1
    v2f sA = pkfma(PW, *(const v2f*)(kw + t), B);
    sA = pkfma(PZ, *(const v2f*)(kz + t), sA);
    sA = pkfma(PY, *(const v2f*)(ky + t), sA);
    sA = pkfma(PX, *(const v2f*)(kx + t), sA);
    // pair B: q = t+2, t+3
    v2f sB = pkfma(PW, *(const v2f*)(kw + t + 2), B);
    sB = pkfma(PZ, *(const v2f*)(kz + t + 2), sB);
    sB = pkfma(PY, *(const v2f*)(ky + t + 2), sB);
    sB = pkfma(PX, *(const v2f*)(kx + t + 2), sB);
    v2f eA = {fast_exp2(sA.x), fast_exp2(sA.y)};
    v2f eB = {fast_exp2(sB.x), fast_exp2(sB.y)};
    dA += eA;
    xA = pkfma(eA, *(const v2f*)(vx + t), xA);
    yA = pkfma(eA, *(const v2f*)(vy + t), yA);
    dB += eB;
    xB = pkfma(eB, *(const v2f*)(vx + t + 2), xB);
    yB = pkfma(eB, *(const v2f*)(vy + t + 2), yB);
  }
  pPart[(i * gridDim.y + qsi) * kLP + pe] =
      make_float4(dA.x + dA.y + dB.x + dB.y,
                  xA.x + xA.y + xB.x + xB.y,
                  yA.x + yA.y + yB.x + yB.y, 0.f);
}

// -------- full-image merge: init + partial-merge + inverse-map scatter, all coalesced --------
__global__ void k_merge_full(const float4* __restrict__ pPart, int QS,
                             const int* __restrict__ hpws, float* __restrict__ out) {
  int i = blockIdx.y;
  int pix = blockIdx.x * 256 + threadIdx.x;   // < kHW
  const int* hp = hpws + i * 20;              // wave-uniform -> scalar loads
  int use = hp[0];
  int ntop_p = hp[7], nleft_p = hp[8], nh_p = hp[9], nw_p = hp[10];
  int r = pix >> 8;          // kW = 256
  int c = pix & 255;
  int pr = r - ntop_p, pc = c - nleft_p;
  bool val = use && ((unsigned)pr < (unsigned)nh_p) && ((unsigned)pc < (unsigned)nw_p);
  float f0 = -1.f, f1 = -1.f, mk = 0.f;
  if (val) {
    int p = pr * kMW + pc;
    float den = -kPadCorr, n0 = kPadCorr, n1 = kPadCorr;  // remove pad-q contribution
    for (int k = 0; k < QS; ++k) {
      float4 t = pPart[(i * QS + k) * kLP + p];
      den += t.x; n0 += t.y; n1 += t.z;
    }
    float inv = 1.0f / den;
    f0 = n0 * inv; f1 = n1 * inv; mk = 1.0f;
  }
  out[(2 * i) * kHW + pix]      = f0;
  out[(2 * i + 1) * kHW + pix]  = f1;
  out[64 * kHW + i * kHW + pix] = mk;
}

extern "C" void kernel_launch(void* const* d_in, const int* in_sizes, int n_in,
                              void* d_out, int out_size, void* d_ws, size_t ws_size,
                              hipStream_t stream) {
  (void)in_sizes; (void)n_in; (void)out_size;
  const float* loc = (const float*)d_in[0];
  const float* fc  = (const float*)d_in[1];
  const float* fp  = (const float*)d_in[2];
  const float* sp  = (const float*)d_in[3];
  const int* clm   = (const int*)d_in[6];
  const int* plm   = (const int*)d_in[7];
  const float* w1  = (const float*)d_in[8];
  const float* b1  = (const float*)d_in[9];
  const float* a1  = (const float*)d_in[10];
  const float* w2  = (const float*)d_in[11];
  const float* b2  = (const float*)d_in[12];
  const float* a2  = (const float*)d_in[13];
  float* out = (float*)d_out;
  char* ws = (char*)d_ws;

  // workspace layout (16B aligned)
  int*    hpws = (int*)(ws);                   // 32*20*4 = 2560 B (pad to 4096)
  float*  Kpl  = (float*)(ws + 4096);          // 4*32*2048*4 = 1,048,576 B
  float*  Vpl  = (float*)(ws + 1052672);       // 2*32*2048*4 =   524,288 B
  float4* Pall = (float4*)(ws + 1576960);      // 32*1989*16  = 1,018,368 B
  size_t base = 2595328;
  size_t perQS = (size_t)kHeads * kLP * 16;    // 1 MiB per q-slice (float4 partials)
  int QS = 1;
  if (ws_size >= base + 16 * perQS) QS = 16;
  else if (ws_size >= base + 8 * perQS) QS = 8;
  else if (ws_size >= base + 4 * perQS) QS = 4;
  else if (ws_size >= base + 2 * perQS) QS = 2;
  float4* pPart = (float4*)(ws + base);

  k_patch<<<dim3(kLP / 256, kHeads), 256, 0, stream>>>(fc, fp, w1, b1, a1, w2, b2, a2,
                                                       loc, sp, clm, plm, Kpl, Vpl, Pall, hpws);
  dim3 ag(8, QS, kHeads);
  switch (QS) {
    case 16: k_attn_t<128><<<ag, 256, 0, stream>>>(Kpl, Vpl, Pall, pPart); break;
    case 8:  k_attn_t<256><<<ag, 256, 0, stream>>>(Kpl, Vpl, Pall, pPart); break;
    case 4:  k_attn_t<512><<<ag, 256, 0, stream>>>(Kpl, Vpl, Pall, pPart); break;
    case 2:  k_attn_t<1024><<<ag, 256, 0, stream>>>(Kpl, Vpl, Pall, pPart); break;
    default: k_attn_t<2048><<<ag, 256, 0, stream>>>(Kpl, Vpl, Pall, pPart); break;
  }
  k_merge_full<<<dim3(kHW / 256, kHeads), 256, 0, stream>>>(pPart, QS, hpws, out);
}